// Round 14
// baseline (474.300 us; speedup 1.0000x reference)
//
#include <hip/hip_runtime.h>
#include <cstddef>

// GIN forward on MI355X — round 14: fuse gather into GEMM1 (gg_kernel).
// Each wave gathers its 16 tile rows into a wave-private LDS tile (packed bf16,
// [16][65] u32 pad -> conflict-free, no barriers), then runs the MFMA phase.
// Bitwise-identical math to R13. 128-thr blocks x 1563 -> ~16 blocks/CU keeps the
// gather phase BW-saturated; kills aggb round trip + 5 dispatches.

namespace {
constexpr int kN = 50000;
constexpr int kE = 800000;
constexpr int kH = 128;
constexpr int kL = 5;
constexpr int kG = 64;
constexpr float kBnEps = 1e-5f;
constexpr int kEPB = 1024;                      // edges per pass-1 block
constexpr int kG1 = (kE + kEPB - 1) / kEPB;     // 782
constexpr int kB = 49;                          // buckets: dst>>10, dst<50000
constexpr int kM = kB * kG1;                    // 38318 scan length
constexpr int kTiles = kN / 16;                 // 3125
constexpr int kGemmGrid = (kTiles + 3) / 4;     // 782
constexpr int kGGGrid = (kTiles + 1) / 2;       // 1563 (2 waves/block)
}

typedef __attribute__((ext_vector_type(8))) short short8v;
typedef __attribute__((ext_vector_type(4))) float f32x4;

__device__ inline unsigned short f2bf(float f) {
    unsigned int u = __float_as_uint(f);
    unsigned int r = (u + 0x7fffu + ((u >> 16) & 1u)) >> 16;  // round-to-nearest-even
    return (unsigned short)r;
}
__device__ inline float bf2f(unsigned int h16) {
    return __uint_as_float(h16 << 16);
}

// ---------------- CSR build, pass 1a: per-block bucket histogram ----------------
__global__ __launch_bounds__(256) void part1a_kernel(const int* __restrict__ dst,
                                                     int* __restrict__ bh) {
    __shared__ int hist[kB];
    const int tid = threadIdx.x;
    if (tid < kB) hist[tid] = 0;
    __syncthreads();
    const int base = blockIdx.x * kEPB;
    for (int i = tid; i < kEPB; i += 256) {
        int e = base + i;
        if (e < kE) atomicAdd(&hist[dst[e] >> 10], 1);
    }
    __syncthreads();
    if (tid < kB) bh[tid * kG1 + blockIdx.x] = hist[tid];  // bucket-major for flat scan
}

// ---------------- parameterized 3-phase exclusive scan ----------------
__global__ __launch_bounds__(512) void scanP1_kernel(const int* __restrict__ in,
                                                     int* __restrict__ loc,
                                                     int* __restrict__ bsum, int n) {
    const int i = blockIdx.x * 512 + threadIdx.x;
    const int lane = threadIdx.x & 63;
    const int wid = threadIdx.x >> 6;
    int v = (i < n) ? in[i] : 0;
    int s = v;
#pragma unroll
    for (int d = 1; d < 64; d <<= 1) {
        int t = __shfl_up(s, d);
        if (lane >= d) s += t;
    }
    __shared__ int wsum[8];
    if (lane == 63) wsum[wid] = s;
    __syncthreads();
    if (threadIdx.x < 8) {
        int w = wsum[threadIdx.x];
#pragma unroll
        for (int d = 1; d < 8; d <<= 1) {
            int t = __shfl_up(w, d);
            if (lane >= d) w += t;
        }
        wsum[threadIdx.x] = w;
    }
    __syncthreads();
    int woff = (wid == 0) ? 0 : wsum[wid - 1];
    int incl = s + woff;
    if (i < n) loc[i] = incl - v;
    if (threadIdx.x == 511) bsum[blockIdx.x] = incl;
}

__global__ void scanP2_kernel(int* __restrict__ bsum, int nb) {
    const int t = threadIdx.x;  // 128
    const int lane = t & 63;
    const int wid = t >> 6;
    int v = (t < nb) ? bsum[t] : 0;
    int s = v;
#pragma unroll
    for (int d = 1; d < 64; d <<= 1) {
        int u = __shfl_up(s, d);
        if (lane >= d) s += u;
    }
    __shared__ int ws[2];
    if (lane == 63) ws[wid] = s;
    __syncthreads();
    int incl = s + ((wid == 1) ? ws[0] : 0);
    if (t < nb) bsum[t] = incl - v;
}

__global__ __launch_bounds__(512) void scanP3_kernel(const int* __restrict__ loc,
                                                     const int* __restrict__ bsum,
                                                     int* __restrict__ outp, int n) {
    const int i = blockIdx.x * 512 + threadIdx.x;
    if (i < n) outp[i] = loc[i] + bsum[blockIdx.x];
}

// ---------------- CSR build, pass 1b: partition edges into buckets ----------------
__global__ __launch_bounds__(256) void part1b_kernel(const int* __restrict__ src,
                                                     const int* __restrict__ dst,
                                                     const int* __restrict__ bhex,
                                                     unsigned int* __restrict__ part) {
    __shared__ int cur[kB];
    const int tid = threadIdx.x;
    if (tid < kB) cur[tid] = bhex[tid * kG1 + blockIdx.x];
    __syncthreads();
    const int base = blockIdx.x * kEPB;
    for (int i = tid; i < kEPB; i += 256) {
        int e = base + i;
        if (e < kE) {
            unsigned int d = (unsigned int)dst[e];
            unsigned int s = (unsigned int)src[e];
            int p = atomicAdd(&cur[d >> 10], 1);
            part[p] = (d << 16) | s;
        }
    }
}

// ---------------- CSR build, pass 2: per-bucket local CSR (rowptr + col) ----------------
__global__ __launch_bounds__(1024) void bucket_kernel(const unsigned int* __restrict__ part,
                                                      const int* __restrict__ bhex,
                                                      int* __restrict__ rowptr,
                                                      int* __restrict__ col) {
    const int b = blockIdx.x;  // 0..48
    const int tid = threadIdx.x;
    const int lane = tid & 63;
    const int wid = tid >> 6;  // 0..15
    const int bstart = bhex[b * kG1];
    const int bend = (b == kB - 1) ? kE : bhex[(b + 1) * kG1];
    __shared__ int lhist[1024];
    __shared__ int wsum[16];
    lhist[tid] = 0;
    __syncthreads();
    for (int e = bstart + tid; e < bend; e += 1024)
        atomicAdd(&lhist[part[e] >> 16 & 1023], 1);
    __syncthreads();
    int v = lhist[tid];
    int s = v;
#pragma unroll
    for (int d = 1; d < 64; d <<= 1) {
        int t = __shfl_up(s, d);
        if (lane >= d) s += t;
    }
    if (lane == 63) wsum[wid] = s;
    __syncthreads();
    if (tid < 16) {
        int w = wsum[tid];
#pragma unroll
        for (int d = 1; d < 16; d <<= 1) {
            int t = __shfl_up(w, d);
            if (lane >= d) w += t;
        }
        wsum[tid] = w;
    }
    __syncthreads();
    int excl = s - v + ((wid == 0) ? 0 : wsum[wid - 1]);
    const int d = (b << 10) + tid;
    if (d < kN) rowptr[d] = bstart + excl;
    __syncthreads();
    lhist[tid] = bstart + excl;  // cursor
    __syncthreads();
    for (int e = bstart + tid; e < bend; e += 1024) {
        unsigned int pv = part[e];
        int p = atomicAdd(&lhist[pv >> 16 & 1023], 1);
        col[p] = (int)(pv & 0xffffu);
    }
    if (b == kB - 1 && tid == 0) rowptr[kN] = kE;
}

// batch is sorted: gp[g] = first row index of graph g, gp[kG] = kN. No atomics.
__global__ void gp_kernel(const int* __restrict__ batch, int* __restrict__ gp) {
    int i = blockIdx.x * blockDim.x + threadIdx.x;
    if (i >= kN) return;
    int b = batch[i];
    if (i == 0) {
        for (int g = 0; g <= b; ++g) gp[g] = 0;
    } else {
        int p = batch[i - 1];
        for (int g = p; g < b; ++g) gp[g + 1] = i;
    }
    if (i == kN - 1) {
        for (int g = b; g < kG; ++g) gp[g + 1] = kN;
    }
}

// ---------------- weight pre-pack: 11 matrices -> MFMA fragment order, bf16 ----
__global__ __launch_bounds__(256) void pack_kernel(const float* __restrict__ W1,
                                                   const float* __restrict__ W2,
                                                   const float* __restrict__ linW,
                                                   short* __restrict__ wpk) {
    const int m = blockIdx.x;  // 0..10
    const float* src = (m < 5) ? W1 + (size_t)m * 16384
                               : (m < 10 ? W2 + (size_t)(m - 5) * 16384 : linW);
    for (int f = threadIdx.x; f < 2048; f += 256) {
        int kc = f >> 9;
        int t = (f >> 6) & 7;
        int l = f & 63;
        int kr = kc * 32 + ((l >> 4) << 3);
        int cl = t * 16 + (l & 15);
        short8v hi;
#pragma unroll
        for (int e = 0; e < 8; ++e)
            hi[e] = (short)f2bf(src[(size_t)(kr + e) * kH + cl]);
        *reinterpret_cast<short8v*>(wpk + (size_t)m * 16384 + (size_t)f * 8) = hi;
    }
}

// ---------------- x -> bf16 h state (layer 0 only) ----------------
__global__ __launch_bounds__(256) void conv_kernel(const float* __restrict__ x,
                                                   unsigned int* __restrict__ hb) {
    int i = blockIdx.x * blockDim.x + threadIdx.x;  // over kN*32 float4s
    if (i >= kN * (kH / 4)) return;
    float4 v = reinterpret_cast<const float4*>(x)[i];
    unsigned int p01 = (unsigned int)f2bf(v.x) | ((unsigned int)f2bf(v.y) << 16);
    unsigned int p23 = (unsigned int)f2bf(v.z) | ((unsigned int)f2bf(v.w) << 16);
    hb[i * 2] = p01;
    hb[i * 2 + 1] = p23;
}

// ---------------- fused gather + GEMM1: 2 waves/block, one 16-row tile per wave -------
// Phase A: wave gathers its 16 rows (8 edges in flight, V1 pattern) into wave-private
// LDS tile aggL[w][16][65] (u32 = 2 packed bf16, +1 pad -> conflict-free).
// Phase B: A = bf16( (1+eps)*hb + aggL ) -> MFMA -> relu -> bf16 hmid. No barriers.
__global__ __launch_bounds__(128) void gg_kernel(const unsigned int* __restrict__ hb,
                                                 const int* __restrict__ rowptr,
                                                 const int* __restrict__ col,
                                                 const short* __restrict__ wpk, int mat,
                                                 const float* __restrict__ bias,
                                                 const float* __restrict__ eps_p, int layer,
                                                 unsigned short* __restrict__ out16) {
    const int lane = threadIdx.x & 63;
    const int w = threadIdx.x >> 6;  // 0..1
    const int tile = blockIdx.x * 2 + w;
    if (tile >= kTiles) return;
    const int row0 = tile * 16;

    __shared__ unsigned int aggL[2][16][65];  // 8.3 KB

    // ---- Phase A: gather ----
    for (int r = 0; r < 16; ++r) {
        const int n = row0 + r;
        const int e0 = rowptr[n], e1 = rowptr[n + 1];
        float ax = 0.f, ay = 0.f, bx = 0.f, by = 0.f;
        float cx = 0.f, cy = 0.f, dx = 0.f, dy = 0.f;
        if (e0 < e1) {
            const int last = e1 - 1;
            for (int e = e0; e < e1; e += 8) {
                int i0, i1, i2, i3, i4, i5, i6, i7;
                float m0, m1, m2, m3, m4, m5, m6, m7;
                {
                    int t;
                    t = e + 0; m0 = (t <= last) ? 1.f : 0.f; i0 = col[t <= last ? t : last];
                    t = e + 1; m1 = (t <= last) ? 1.f : 0.f; i1 = col[t <= last ? t : last];
                    t = e + 2; m2 = (t <= last) ? 1.f : 0.f; i2 = col[t <= last ? t : last];
                    t = e + 3; m3 = (t <= last) ? 1.f : 0.f; i3 = col[t <= last ? t : last];
                    t = e + 4; m4 = (t <= last) ? 1.f : 0.f; i4 = col[t <= last ? t : last];
                    t = e + 5; m5 = (t <= last) ? 1.f : 0.f; i5 = col[t <= last ? t : last];
                    t = e + 6; m6 = (t <= last) ? 1.f : 0.f; i6 = col[t <= last ? t : last];
                    t = e + 7; m7 = (t <= last) ? 1.f : 0.f; i7 = col[t <= last ? t : last];
                }
                unsigned int u0 = hb[(size_t)i0 * 64 + lane];
                unsigned int u1 = hb[(size_t)i1 * 64 + lane];
                unsigned int u2 = hb[(size_t)i2 * 64 + lane];
                unsigned int u3 = hb[(size_t)i3 * 64 + lane];
                unsigned int u4 = hb[(size_t)i4 * 64 + lane];
                unsigned int u5 = hb[(size_t)i5 * 64 + lane];
                unsigned int u6 = hb[(size_t)i6 * 64 + lane];
                unsigned int u7 = hb[(size_t)i7 * 64 + lane];
                ax = fmaf(m0, bf2f(u0 & 0xffffu), ax); ay = fmaf(m0, bf2f(u0 >> 16), ay);
                bx = fmaf(m1, bf2f(u1 & 0xffffu), bx); by = fmaf(m1, bf2f(u1 >> 16), by);
                cx = fmaf(m2, bf2f(u2 & 0xffffu), cx); cy = fmaf(m2, bf2f(u2 >> 16), cy);
                dx = fmaf(m3, bf2f(u3 & 0xffffu), dx); dy = fmaf(m3, bf2f(u3 >> 16), dy);
                ax = fmaf(m4, bf2f(u4 & 0xffffu), ax); ay = fmaf(m4, bf2f(u4 >> 16), ay);
                bx = fmaf(m5, bf2f(u5 & 0xffffu), bx); by = fmaf(m5, bf2f(u5 >> 16), by);
                cx = fmaf(m6, bf2f(u6 & 0xffffu), cx); cy = fmaf(m6, bf2f(u6 >> 16), cy);
                dx = fmaf(m7, bf2f(u7 & 0xffffu), dx); dy = fmaf(m7, bf2f(u7 >> 16), dy);
            }
        }
        float sx = (ax + bx) + (cx + dx), sy = (ay + by) + (cy + dy);
        aggL[w][r][lane] = (unsigned int)f2bf(sx) | ((unsigned int)f2bf(sy) << 16);
    }
    // wave-private LDS tile: ds ops complete in wave order; no barrier needed.

    // ---- Phase B: GEMM1 ----
    const int m15 = lane & 15;
    const int kg = lane >> 4;
    const int arow = row0 + m15;
    const float scale = 1.0f + eps_p[layer];
    const unsigned short* hb16 = reinterpret_cast<const unsigned short*>(hb);
    const short8v* wp = reinterpret_cast<const short8v*>(wpk + (size_t)mat * 16384);

    f32x4 acc[8];
#pragma unroll
    for (int t = 0; t < 8; ++t) acc[t] = (f32x4)0.0f;

#pragma unroll
    for (int kc = 0; kc < 4; ++kc) {
        short8v hv = *reinterpret_cast<const short8v*>(hb16 + (size_t)arow * kH + kc * 32 +
                                                       kg * 8);
        short8v ah;
#pragma unroll
        for (int j = 0; j < 4; ++j) {
            unsigned int u = aggL[w][m15][kc * 16 + kg * 4 + j];
            float a0 = fmaf(scale, bf2f((unsigned short)hv[2 * j]), bf2f(u & 0xffffu));
            float a1 = fmaf(scale, bf2f((unsigned short)hv[2 * j + 1]), bf2f(u >> 16));
            ah[2 * j] = (short)f2bf(a0);
            ah[2 * j + 1] = (short)f2bf(a1);
        }
#pragma unroll
        for (int t = 0; t < 8; ++t) {
            int f = (kc * 8 + t) * 64 + lane;
            acc[t] = __builtin_amdgcn_mfma_f32_16x16x32_bf16(ah, wp[f], acc[t], 0, 0, 0);
        }
    }

    const int orow0 = row0 + kg * 4;
#pragma unroll
    for (int t = 0; t < 8; ++t) {
        int cl = t * 16 + m15;
        float b = bias[cl];
#pragma unroll
        for (int r = 0; r < 4; ++r)
            out16[(size_t)(orow0 + r) * kH + cl] = f2bf(fmaxf(acc[t][r] + b, 0.f));
    }
}

// ---------------- MFMA GEMM: one wave = 16 rows x 128 cols, all-bf16, 1-term ----------
// MODE 1: A = Aa direct -> relu -> bf16 out16 (h2) + per-block stats partials
// MODE 2: A = Aa direct -> tanh -> fp32 out32 (y)
template <int MODE>
__global__ __launch_bounds__(256) void mfma_gemm(const unsigned short* __restrict__ Aa,
                                                 const short* __restrict__ wpk, int mat,
                                                 const float* __restrict__ bias,
                                                 float* __restrict__ out32,
                                                 unsigned short* __restrict__ out16,
                                                 float* __restrict__ spart) {
    const int lane = threadIdx.x & 63;
    const int wid = threadIdx.x >> 6;
    const int tile = blockIdx.x * 4 + wid;
    const bool valid = (tile < kTiles);
    if (MODE != 1 && !valid) return;
    const int row0 = tile * 16;
    const int m15 = lane & 15;
    const int kg = lane >> 4;  // 0..3
    const int arow = row0 + m15;

    const short8v* wp = reinterpret_cast<const short8v*>(wpk + (size_t)mat * 16384);

    f32x4 acc[8];
#pragma unroll
    for (int t = 0; t < 8; ++t) acc[t] = (f32x4)0.0f;

    if (valid) {
#pragma unroll
        for (int kc = 0; kc < 4; ++kc) {
            short8v ah = *reinterpret_cast<const short8v*>(Aa + (size_t)arow * kH + kc * 32 +
                                                           kg * 8);
#pragma unroll
            for (int t = 0; t < 8; ++t) {
                int f = (kc * 8 + t) * 64 + lane;
                acc[t] = __builtin_amdgcn_mfma_f32_16x16x32_bf16(ah, wp[f], acc[t], 0, 0, 0);
            }
        }
    }

    const int orow0 = row0 + kg * 4;
    if (MODE == 2) {
#pragma unroll
        for (int t = 0; t < 8; ++t) {
            int cl = t * 16 + m15;
            float b = bias[cl];
#pragma unroll
            for (int r = 0; r < 4; ++r)
                out32[(size_t)(orow0 + r) * kH + cl] = tanhf(acc[t][r] + b);
        }
    } else {
        __shared__ float sst[4][kH], sqt[4][kH];
#pragma unroll
        for (int t = 0; t < 8; ++t) {
            int cl = t * 16 + m15;
            float b = bias[cl];
            float st = 0.f, qt = 0.f;
#pragma unroll
            for (int r = 0; r < 4; ++r) {
                float o = fmaxf(acc[t][r] + b, 0.f);
                unsigned short h16 = f2bf(o);
                if (valid) out16[(size_t)(orow0 + r) * kH + cl] = h16;
                float orr = bf2f(h16);  // stats from the rounded value bn will read
                st += orr;
                qt = fmaf(orr, orr, qt);
            }
            if (!valid) { st = 0.f; qt = 0.f; }
            st += __shfl_xor(st, 16); st += __shfl_xor(st, 32);
            qt += __shfl_xor(qt, 16); qt += __shfl_xor(qt, 32);
            if (kg == 0) { sst[wid][cl] = st; sqt[wid][cl] = qt; }
        }
        __syncthreads();
        int c = threadIdx.x;
        float v;
        if (c < kH) v = sst[0][c] + sst[1][c] + sst[2][c] + sst[3][c];
        else { int cc = c - kH; v = sqt[0][cc] + sqt[1][cc] + sqt[2][cc] + sqt[3][cc]; }
        spart[(size_t)blockIdx.x * 256 + c] = v;
    }
}

// ---------------- fold per-block partials into stats (sums[128] | sumsq[128]) ----------
__global__ __launch_bounds__(256) void stats3_kernel(const float* __restrict__ spart,
                                                     float* __restrict__ stats) {
    const int c = threadIdx.x;  // 0..255
    float s = 0.f;
    for (int k = blockIdx.x; k < kGemmGrid; k += gridDim.x)
        s += spart[(size_t)k * 256 + c];
    atomicAdd(&stats[c], s);
}

// ---------------- two-phase segment mean pool ----------------
__global__ __launch_bounds__(256) void pool1_kernel(const float* __restrict__ y,
                                                    const int* __restrict__ gp,
                                                    float* __restrict__ partial) {
    const int g = blockIdx.x >> 4;
    const int s = blockIdx.x & 15;
    const int c = threadIdx.x & 127;
    const int q = threadIdx.x >> 7;  // 0..1
    const int rs = gp[g], re = gp[g + 1];
    float acc = 0.f;
    for (int r = rs + s * 2 + q; r < re; r += 32) acc += y[(size_t)r * kH + c];
    __shared__ float part[2][kH];
    part[q][c] = acc;
    __syncthreads();
    if (q == 0) partial[(size_t)blockIdx.x * kH + c] = part[0][c] + part[1][c];
}

__global__ void pool2_kernel(const float* __restrict__ partial, const int* __restrict__ gp,
                             float* __restrict__ out) {
    const int g = blockIdx.x;
    const int c = threadIdx.x;  // 128
    float v = 0.f;
#pragma unroll
    for (int s = 0; s < 16; ++s) v += partial[(size_t)((g << 4) + s) * kH + c];
    out[g * kH + c] = v / fmaxf((float)(gp[g + 1] - gp[g]), 1.0f);
}

// ---------------- BN (+ relu + residual for l>0), all-bf16 state ----------------
__global__ __launch_bounds__(256) void bn_kernel(const uint2* __restrict__ h2b,
                                                 uint2* __restrict__ hb,
                                                 const float* __restrict__ gamma,
                                                 const float* __restrict__ beta,
                                                 const float* __restrict__ sums,
                                                 const float* __restrict__ sumsq,
                                                 int first) {
    const float invN = 1.0f / (float)kN;
    const size_t total = (size_t)kN * (kH / 4);
    const size_t stride = (size_t)gridDim.x * blockDim.x;
    for (size_t i = (size_t)blockIdx.x * blockDim.x + threadIdx.x; i < total; i += stride) {
        int c0 = ((int)(i & 31)) * 4;
        float4 s4 = *reinterpret_cast<const float4*>(sums + c0);
        float4 q4 = *reinterpret_cast<const float4*>(sumsq + c0);
        float4 g4 = *reinterpret_cast<const float4*>(gamma + c0);
        float4 be4 = *reinterpret_cast<const float4*>(beta + c0);
        uint2 hv = h2b[i];
        float v0 = bf2f(hv.x & 0xffffu), v1 = bf2f(hv.x >> 16);
        float v2 = bf2f(hv.y & 0xffffu), v3 = bf2f(hv.y >> 16);
        float o0, o1, o2, o3;
        {
            float mu = s4.x * invN, var = fmaxf(q4.x * invN - mu * mu, 0.f);
            o0 = (v0 - mu) * rsqrtf(var + kBnEps) * g4.x + be4.x;
        }
        {
            float mu = s4.y * invN, var = fmaxf(q4.y * invN - mu * mu, 0.f);
            o1 = (v1 - mu) * rsqrtf(var + kBnEps) * g4.y + be4.y;
        }
        {
            float mu = s4.z * invN, var = fmaxf(q4.z * invN - mu * mu, 0.f);
            o2 = (v2 - mu) * rsqrtf(var + kBnEps) * g4.z + be4.z;
        }
        {
            float mu = s4.w * invN, var = fmaxf(q4.w * invN - mu * mu, 0.f);
            o3 = (v3 - mu) * rsqrtf(var + kBnEps) * g4.w + be4.w;
        }
        float r0, r1, r2, r3;
        if (first) {
            r0 = o0; r1 = o1; r2 = o2; r3 = o3;
        } else {
            uint2 pv = hb[i];
            r0 = bf2f(pv.x & 0xffffu) + fmaxf(o0, 0.f);
            r1 = bf2f(pv.x >> 16) + fmaxf(o1, 0.f);
            r2 = bf2f(pv.y & 0xffffu) + fmaxf(o2, 0.f);
            r3 = bf2f(pv.y >> 16) + fmaxf(o3, 0.f);
        }
        uint2 w;
        w.x = (unsigned int)f2bf(r0) | ((unsigned int)f2bf(r1) << 16);
        w.y = (unsigned int)f2bf(r2) | ((unsigned int)f2bf(r3) << 16);
        hb[i] = w;
    }
}

// ---------------- launch ----------------
extern "C" void kernel_launch(void* const* d_in, const int* in_sizes, int n_in,
                              void* d_out, int out_size, void* d_ws, size_t ws_size,
                              hipStream_t stream) {
    const float* x     = (const float*)d_in[0];
    const int*   ei    = (const int*)d_in[1];
    const int*   batch = (const int*)d_in[2];
    const float* W1    = (const float*)d_in[3];
    const float* b1    = (const float*)d_in[4];
    const float* W2    = (const float*)d_in[5];
    const float* b2    = (const float*)d_in[6];
    const float* gamma = (const float*)d_in[7];
    const float* beta  = (const float*)d_in[8];
    const float* eps   = (const float*)d_in[9];
    const float* linW  = (const float*)d_in[10];
    const float* linb  = (const float*)d_in[11];
    float* out = (float*)d_out;

    char* ws = (char*)d_ws;
    size_t off = 0;
    auto alloc = [&](size_t bytes) -> char* {
        char* p = ws + off;
        off = (off + bytes + 15) & ~(size_t)15;
        return p;
    };
    unsigned int*   hb     = (unsigned int*)alloc((size_t)kN * kH * 2);   // bf16 h state
    unsigned short* hmid16 = (unsigned short*)alloc((size_t)kN * kH * 2); // bf16 MLP hidden
    unsigned short* h2b    = (unsigned short*)alloc((size_t)kN * kH * 2); // bf16 h2 (pre-BN)
    float* ybuf   = (float*)alloc((size_t)kN * kH * 4);  // final tanh output
    float* ppart  = (float*)alloc((size_t)kG * 16 * kH * 4);
    int*   rowptr = (int*)alloc((size_t)(kN + 1) * 4);
    int*   colidx = (int*)alloc((size_t)kE * 4);
    unsigned int* part = (unsigned int*)alloc((size_t)kE * 4);  // packed (dst<<16)|src
    int*   bh_in  = (int*)alloc((size_t)kM * 4);
    int*   bh_loc = (int*)alloc((size_t)kM * 4);
    int*   bh_ex  = (int*)alloc((size_t)kM * 4);
    int*   sbp    = (int*)alloc((size_t)128 * 4);
    float* stats  = (float*)alloc((size_t)kL * 256 * 4);
    float* spart  = (float*)alloc((size_t)kGemmGrid * 256 * 4);
    int*   gp     = (int*)alloc((size_t)(kG + 1) * 4);
    short* wpk    = (short*)alloc((size_t)11 * 16384 * 2);  // bf16 fragments

    const int* srcp = ei;       // edge_index[0] (source)
    const int* dstp = ei + kE;  // edge_index[1] (target)

    hipMemsetAsync(stats, 0, (size_t)kL * 256 * 4, stream);

    const int scanBlocks = (kM + 511) / 512;  // 75
    part1a_kernel<<<kG1, 256, 0, stream>>>(dstp, bh_in);
    scanP1_kernel<<<scanBlocks, 512, 0, stream>>>(bh_in, bh_loc, sbp, kM);
    scanP2_kernel<<<1, 128, 0, stream>>>(sbp, scanBlocks);
    scanP3_kernel<<<scanBlocks, 512, 0, stream>>>(bh_loc, sbp, bh_ex, kM);
    part1b_kernel<<<kG1, 256, 0, stream>>>(srcp, dstp, bh_ex, part);
    bucket_kernel<<<kB, 1024, 0, stream>>>(part, bh_ex, rowptr, colidx);
    gp_kernel<<<(kN + 255) / 256, 256, 0, stream>>>(batch, gp);
    pack_kernel<<<11, 256, 0, stream>>>(W1, W2, linW, wpk);
    conv_kernel<<<(kN * (kH / 4) + 255) / 256, 256, 0, stream>>>(x, hb);

    for (int l = 0; l < kL; ++l) {
        gg_kernel<<<kGGGrid, 128, 0, stream>>>(hb, rowptr, colidx, wpk, l,
                                               b1 + (size_t)l * kH, eps, l, hmid16);
        mfma_gemm<1><<<kGemmGrid, 256, 0, stream>>>(hmid16, wpk, 5 + l,
                                                    b2 + (size_t)l * kH, nullptr, h2b,
                                                    spart);
        stats3_kernel<<<64, 256, 0, stream>>>(spart, stats + l * 256);
        bn_kernel<<<2048, 256, 0, stream>>>((const uint2*)h2b, (uint2*)hb,
                                            gamma + (size_t)l * kH, beta + (size_t)l * kH,
                                            stats + l * 256, stats + l * 256 + 128,
                                            l == 0 ? 1 : 0);
    }
    mfma_gemm<2><<<kGemmGrid, 256, 0, stream>>>((const unsigned short*)hb, wpk, 10, linb,
                                                ybuf, nullptr, nullptr);
    pool1_kernel<<<kG * 16, 256, 0, stream>>>(ybuf, gp, ppart);
    pool2_kernel<<<kG, kH, 0, stream>>>(ppart, gp, out);
}

// Round 15
// 405.017 us; speedup vs baseline: 1.1711x; 1.1711x over previous
//
#include <hip/hip_runtime.h>
#include <cstddef>

// GIN forward on MI355X — round 15: revert R14 fusion (gather must keep 50k waves).
// R13 structure + fp8-e4m3 gather mirror: bn/conv co-write h8 (HW cvt_pk_fp8_f32);
// gather reads 128B fp8 rows (half the random-read traffic), accumulates fp32,
// writes bf16 aggb. GEMM/residual path stays bf16 (unchanged quality).

namespace {
constexpr int kN = 50000;
constexpr int kE = 800000;
constexpr int kH = 128;
constexpr int kL = 5;
constexpr int kG = 64;
constexpr float kBnEps = 1e-5f;
constexpr int kEPB = 1024;                      // edges per pass-1 block
constexpr int kG1 = (kE + kEPB - 1) / kEPB;     // 782
constexpr int kB = 49;                          // buckets: dst>>10, dst<50000
constexpr int kM = kB * kG1;                    // 38318 scan length
constexpr int kTiles = kN / 16;                 // 3125
constexpr int kGemmGrid = (kTiles + 3) / 4;     // 782
}

typedef __attribute__((ext_vector_type(8))) short short8v;
typedef __attribute__((ext_vector_type(4))) float f32x4;

__device__ inline unsigned short f2bf(float f) {
    unsigned int u = __float_as_uint(f);
    unsigned int r = (u + 0x7fffu + ((u >> 16) & 1u)) >> 16;  // round-to-nearest-even
    return (unsigned short)r;
}
__device__ inline float bf2f(unsigned int h16) {
    return __uint_as_float(h16 << 16);
}
// pack 4 floats -> 4 fp8 e4m3 (OCP on gfx950), RNE
__device__ inline unsigned int pk_fp8(float a, float b, float c, float d) {
    int p = 0;
    p = __builtin_amdgcn_cvt_pk_fp8_f32(a, b, p, false);
    p = __builtin_amdgcn_cvt_pk_fp8_f32(c, d, p, true);
    return (unsigned int)p;
}

// ---------------- CSR build, pass 1a: per-block bucket histogram ----------------
__global__ __launch_bounds__(256) void part1a_kernel(const int* __restrict__ dst,
                                                     int* __restrict__ bh) {
    __shared__ int hist[kB];
    const int tid = threadIdx.x;
    if (tid < kB) hist[tid] = 0;
    __syncthreads();
    const int base = blockIdx.x * kEPB;
    for (int i = tid; i < kEPB; i += 256) {
        int e = base + i;
        if (e < kE) atomicAdd(&hist[dst[e] >> 10], 1);
    }
    __syncthreads();
    if (tid < kB) bh[tid * kG1 + blockIdx.x] = hist[tid];  // bucket-major for flat scan
}

// ---------------- parameterized 3-phase exclusive scan ----------------
__global__ __launch_bounds__(512) void scanP1_kernel(const int* __restrict__ in,
                                                     int* __restrict__ loc,
                                                     int* __restrict__ bsum, int n) {
    const int i = blockIdx.x * 512 + threadIdx.x;
    const int lane = threadIdx.x & 63;
    const int wid = threadIdx.x >> 6;
    int v = (i < n) ? in[i] : 0;
    int s = v;
#pragma unroll
    for (int d = 1; d < 64; d <<= 1) {
        int t = __shfl_up(s, d);
        if (lane >= d) s += t;
    }
    __shared__ int wsum[8];
    if (lane == 63) wsum[wid] = s;
    __syncthreads();
    if (threadIdx.x < 8) {
        int w = wsum[threadIdx.x];
#pragma unroll
        for (int d = 1; d < 8; d <<= 1) {
            int t = __shfl_up(w, d);
            if (lane >= d) w += t;
        }
        wsum[threadIdx.x] = w;
    }
    __syncthreads();
    int woff = (wid == 0) ? 0 : wsum[wid - 1];
    int incl = s + woff;
    if (i < n) loc[i] = incl - v;
    if (threadIdx.x == 511) bsum[blockIdx.x] = incl;
}

__global__ void scanP2_kernel(int* __restrict__ bsum, int nb) {
    const int t = threadIdx.x;  // 128
    const int lane = t & 63;
    const int wid = t >> 6;
    int v = (t < nb) ? bsum[t] : 0;
    int s = v;
#pragma unroll
    for (int d = 1; d < 64; d <<= 1) {
        int u = __shfl_up(s, d);
        if (lane >= d) s += u;
    }
    __shared__ int ws[2];
    if (lane == 63) ws[wid] = s;
    __syncthreads();
    int incl = s + ((wid == 1) ? ws[0] : 0);
    if (t < nb) bsum[t] = incl - v;
}

__global__ __launch_bounds__(512) void scanP3_kernel(const int* __restrict__ loc,
                                                     const int* __restrict__ bsum,
                                                     int* __restrict__ outp, int n) {
    const int i = blockIdx.x * 512 + threadIdx.x;
    if (i < n) outp[i] = loc[i] + bsum[blockIdx.x];
}

// ---------------- CSR build, pass 1b: partition edges into buckets ----------------
__global__ __launch_bounds__(256) void part1b_kernel(const int* __restrict__ src,
                                                     const int* __restrict__ dst,
                                                     const int* __restrict__ bhex,
                                                     unsigned int* __restrict__ part) {
    __shared__ int cur[kB];
    const int tid = threadIdx.x;
    if (tid < kB) cur[tid] = bhex[tid * kG1 + blockIdx.x];
    __syncthreads();
    const int base = blockIdx.x * kEPB;
    for (int i = tid; i < kEPB; i += 256) {
        int e = base + i;
        if (e < kE) {
            unsigned int d = (unsigned int)dst[e];
            unsigned int s = (unsigned int)src[e];
            int p = atomicAdd(&cur[d >> 10], 1);
            part[p] = (d << 16) | s;
        }
    }
}

// ---------------- CSR build, pass 2: per-bucket local CSR (rowptr + col) ----------------
__global__ __launch_bounds__(1024) void bucket_kernel(const unsigned int* __restrict__ part,
                                                      const int* __restrict__ bhex,
                                                      int* __restrict__ rowptr,
                                                      int* __restrict__ col) {
    const int b = blockIdx.x;  // 0..48
    const int tid = threadIdx.x;
    const int lane = tid & 63;
    const int wid = tid >> 6;  // 0..15
    const int bstart = bhex[b * kG1];
    const int bend = (b == kB - 1) ? kE : bhex[(b + 1) * kG1];
    __shared__ int lhist[1024];
    __shared__ int wsum[16];
    lhist[tid] = 0;
    __syncthreads();
    for (int e = bstart + tid; e < bend; e += 1024)
        atomicAdd(&lhist[part[e] >> 16 & 1023], 1);
    __syncthreads();
    int v = lhist[tid];
    int s = v;
#pragma unroll
    for (int d = 1; d < 64; d <<= 1) {
        int t = __shfl_up(s, d);
        if (lane >= d) s += t;
    }
    if (lane == 63) wsum[wid] = s;
    __syncthreads();
    if (tid < 16) {
        int w = wsum[tid];
#pragma unroll
        for (int d = 1; d < 16; d <<= 1) {
            int t = __shfl_up(w, d);
            if (lane >= d) w += t;
        }
        wsum[tid] = w;
    }
    __syncthreads();
    int excl = s - v + ((wid == 0) ? 0 : wsum[wid - 1]);
    const int d = (b << 10) + tid;
    if (d < kN) rowptr[d] = bstart + excl;
    __syncthreads();
    lhist[tid] = bstart + excl;  // cursor
    __syncthreads();
    for (int e = bstart + tid; e < bend; e += 1024) {
        unsigned int pv = part[e];
        int p = atomicAdd(&lhist[pv >> 16 & 1023], 1);
        col[p] = (int)(pv & 0xffffu);
    }
    if (b == kB - 1 && tid == 0) rowptr[kN] = kE;
}

// batch is sorted: gp[g] = first row index of graph g, gp[kG] = kN. No atomics.
__global__ void gp_kernel(const int* __restrict__ batch, int* __restrict__ gp) {
    int i = blockIdx.x * blockDim.x + threadIdx.x;
    if (i >= kN) return;
    int b = batch[i];
    if (i == 0) {
        for (int g = 0; g <= b; ++g) gp[g] = 0;
    } else {
        int p = batch[i - 1];
        for (int g = p; g < b; ++g) gp[g + 1] = i;
    }
    if (i == kN - 1) {
        for (int g = b; g < kG; ++g) gp[g + 1] = kN;
    }
}

// ---------------- weight pre-pack: 11 matrices -> MFMA fragment order, bf16 ----
__global__ __launch_bounds__(256) void pack_kernel(const float* __restrict__ W1,
                                                   const float* __restrict__ W2,
                                                   const float* __restrict__ linW,
                                                   short* __restrict__ wpk) {
    const int m = blockIdx.x;  // 0..10
    const float* src = (m < 5) ? W1 + (size_t)m * 16384
                               : (m < 10 ? W2 + (size_t)(m - 5) * 16384 : linW);
    for (int f = threadIdx.x; f < 2048; f += 256) {
        int kc = f >> 9;
        int t = (f >> 6) & 7;
        int l = f & 63;
        int kr = kc * 32 + ((l >> 4) << 3);
        int cl = t * 16 + (l & 15);
        short8v hi;
#pragma unroll
        for (int e = 0; e < 8; ++e)
            hi[e] = (short)f2bf(src[(size_t)(kr + e) * kH + cl]);
        *reinterpret_cast<short8v*>(wpk + (size_t)m * 16384 + (size_t)f * 8) = hi;
    }
}

// ---------------- x -> bf16 h state + fp8 gather mirror (layer 0 only) ----------------
__global__ __launch_bounds__(256) void conv_kernel(const float* __restrict__ x,
                                                   unsigned int* __restrict__ hb,
                                                   unsigned int* __restrict__ h8) {
    int i = blockIdx.x * blockDim.x + threadIdx.x;  // over kN*32 float4s
    if (i >= kN * (kH / 4)) return;
    float4 v = reinterpret_cast<const float4*>(x)[i];
    unsigned int p01 = (unsigned int)f2bf(v.x) | ((unsigned int)f2bf(v.y) << 16);
    unsigned int p23 = (unsigned int)f2bf(v.z) | ((unsigned int)f2bf(v.w) << 16);
    hb[i * 2] = p01;
    hb[i * 2 + 1] = p23;
    h8[i] = pk_fp8(v.x, v.y, v.z, v.w);
}

// ---------------- aggregation: aggb[n] = bf16( sum_{j in N(n)} fp8 h8[col[j]] ) ------
// One wave per node. 32 lanes x uint = full 128B fp8 row; two edge-parity groups
// (sub = lane>>5) -> 16 row loads in flight; fp32 accumulate; shfl_xor(32) merge.
__global__ __launch_bounds__(256) void gather_kernel(const unsigned int* __restrict__ h8,
                                                     const int* __restrict__ rowptr,
                                                     const int* __restrict__ col,
                                                     uint2* __restrict__ aggb2) {
    const int lane = threadIdx.x & 63;
    const int sub = lane >> 5;   // edge parity group
    const int cl = lane & 31;    // uint column group (4 fp8 = cols 4cl..4cl+3)
    const int n = blockIdx.x * 4 + (threadIdx.x >> 6);
    if (n >= kN) return;
    const int e0 = rowptr[n], e1 = rowptr[n + 1];
    if (e0 == e1) {
        if (sub == 0) aggb2[(size_t)n * 32 + cl] = make_uint2(0u, 0u);
        return;
    }
    const int last = e1 - 1;
    float a0 = 0.f, a1 = 0.f, a2 = 0.f, a3 = 0.f;
    float b0 = 0.f, b1 = 0.f, b2 = 0.f, b3 = 0.f;
    for (int e = e0; e < e1; e += 16) {
        int idx[8];
        float msk[8];
#pragma unroll
        for (int j = 0; j < 8; ++j) {
            int t = e + 2 * j + sub;
            msk[j] = (t <= last) ? 1.f : 0.f;
            idx[j] = col[t <= last ? t : last];
        }
        unsigned int v[8];
#pragma unroll
        for (int j = 0; j < 8; ++j) v[j] = h8[(size_t)idx[j] * 32 + cl];
#pragma unroll
        for (int j = 0; j < 8; ++j) {
            float x0 = __builtin_amdgcn_cvt_f32_fp8((int)v[j], 0);
            float x1 = __builtin_amdgcn_cvt_f32_fp8((int)v[j], 1);
            float x2 = __builtin_amdgcn_cvt_f32_fp8((int)v[j], 2);
            float x3 = __builtin_amdgcn_cvt_f32_fp8((int)v[j], 3);
            if (j & 1) {
                b0 = fmaf(msk[j], x0, b0); b1 = fmaf(msk[j], x1, b1);
                b2 = fmaf(msk[j], x2, b2); b3 = fmaf(msk[j], x3, b3);
            } else {
                a0 = fmaf(msk[j], x0, a0); a1 = fmaf(msk[j], x1, a1);
                a2 = fmaf(msk[j], x2, a2); a3 = fmaf(msk[j], x3, a3);
            }
        }
    }
    float s0 = a0 + b0, s1 = a1 + b1, s2 = a2 + b2, s3 = a3 + b3;
    s0 += __shfl_xor(s0, 32);
    s1 += __shfl_xor(s1, 32);
    s2 += __shfl_xor(s2, 32);
    s3 += __shfl_xor(s3, 32);
    if (sub == 0) {
        uint2 w;
        w.x = (unsigned int)f2bf(s0) | ((unsigned int)f2bf(s1) << 16);
        w.y = (unsigned int)f2bf(s2) | ((unsigned int)f2bf(s3) << 16);
        aggb2[(size_t)n * 32 + cl] = w;
    }
}

// ---------------- MFMA GEMM: one wave = 16 rows x 128 cols, all-bf16, 1-term ----------
// MODE 0: A = bf16( (1+eps)*Aa + Ab ) -> relu -> bf16 out16 (hmid)
// MODE 1: A = Aa direct -> relu -> bf16 out16 (h2) + per-block stats partials
// MODE 2: A = Aa direct -> tanh -> fp32 out32 (y)
template <int MODE>
__global__ __launch_bounds__(256) void mfma_gemm(const unsigned short* __restrict__ Aa,
                                                 const unsigned short* __restrict__ Ab,
                                                 const short* __restrict__ wpk, int mat,
                                                 const float* __restrict__ bias,
                                                 const float* __restrict__ eps_p, int layer,
                                                 float* __restrict__ out32,
                                                 unsigned short* __restrict__ out16,
                                                 float* __restrict__ spart) {
    const int lane = threadIdx.x & 63;
    const int wid = threadIdx.x >> 6;
    const int tile = blockIdx.x * 4 + wid;
    const bool valid = (tile < kTiles);
    if (MODE != 1 && !valid) return;
    const int row0 = tile * 16;
    const int m15 = lane & 15;
    const int kg = lane >> 4;  // 0..3
    const int arow = row0 + m15;

    float scale = 1.0f;
    if (MODE == 0) scale = 1.0f + eps_p[layer];

    const short8v* wp = reinterpret_cast<const short8v*>(wpk + (size_t)mat * 16384);

    f32x4 acc[8];
#pragma unroll
    for (int t = 0; t < 8; ++t) acc[t] = (f32x4)0.0f;

    if (valid) {
#pragma unroll
        for (int kc = 0; kc < 4; ++kc) {
            short8v ah;
            if (MODE == 0) {
                short8v hv = *reinterpret_cast<const short8v*>(Aa + (size_t)arow * kH +
                                                               kc * 32 + kg * 8);
                short8v gv = *reinterpret_cast<const short8v*>(Ab + (size_t)arow * kH +
                                                               kc * 32 + kg * 8);
#pragma unroll
                for (int e = 0; e < 8; ++e) {
                    float a = fmaf(scale, bf2f((unsigned short)hv[e]),
                                   bf2f((unsigned short)gv[e]));
                    ah[e] = (short)f2bf(a);
                }
            } else {
                ah = *reinterpret_cast<const short8v*>(Aa + (size_t)arow * kH + kc * 32 +
                                                       kg * 8);
            }
#pragma unroll
            for (int t = 0; t < 8; ++t) {
                int f = (kc * 8 + t) * 64 + lane;
                acc[t] = __builtin_amdgcn_mfma_f32_16x16x32_bf16(ah, wp[f], acc[t], 0, 0, 0);
            }
        }
    }

    const int orow0 = row0 + kg * 4;
    if (MODE == 0) {
#pragma unroll
        for (int t = 0; t < 8; ++t) {
            int cl = t * 16 + m15;
            float b = bias[cl];
#pragma unroll
            for (int r = 0; r < 4; ++r)
                out16[(size_t)(orow0 + r) * kH + cl] = f2bf(fmaxf(acc[t][r] + b, 0.f));
        }
    } else if (MODE == 2) {
#pragma unroll
        for (int t = 0; t < 8; ++t) {
            int cl = t * 16 + m15;
            float b = bias[cl];
#pragma unroll
            for (int r = 0; r < 4; ++r)
                out32[(size_t)(orow0 + r) * kH + cl] = tanhf(acc[t][r] + b);
        }
    } else {
        __shared__ float sst[4][kH], sqt[4][kH];
#pragma unroll
        for (int t = 0; t < 8; ++t) {
            int cl = t * 16 + m15;
            float b = bias[cl];
            float st = 0.f, qt = 0.f;
#pragma unroll
            for (int r = 0; r < 4; ++r) {
                float o = fmaxf(acc[t][r] + b, 0.f);
                unsigned short h16 = f2bf(o);
                if (valid) out16[(size_t)(orow0 + r) * kH + cl] = h16;
                float orr = bf2f(h16);  // stats from the rounded value bn will read
                st += orr;
                qt = fmaf(orr, orr, qt);
            }
            if (!valid) { st = 0.f; qt = 0.f; }
            st += __shfl_xor(st, 16); st += __shfl_xor(st, 32);
            qt += __shfl_xor(qt, 16); qt += __shfl_xor(qt, 32);
            if (kg == 0) { sst[wid][cl] = st; sqt[wid][cl] = qt; }
        }
        __syncthreads();
        int c = threadIdx.x;
        float v;
        if (c < kH) v = sst[0][c] + sst[1][c] + sst[2][c] + sst[3][c];
        else { int cc = c - kH; v = sqt[0][cc] + sqt[1][cc] + sqt[2][cc] + sqt[3][cc]; }
        spart[(size_t)blockIdx.x * 256 + c] = v;
    }
}

// ---------------- fold per-block partials into stats (sums[128] | sumsq[128]) ----------
__global__ __launch_bounds__(256) void stats3_kernel(const float* __restrict__ spart,
                                                     float* __restrict__ stats) {
    const int c = threadIdx.x;  // 0..255
    float s = 0.f;
    for (int k = blockIdx.x; k < kGemmGrid; k += gridDim.x)
        s += spart[(size_t)k * 256 + c];
    atomicAdd(&stats[c], s);
}

// ---------------- two-phase segment mean pool ----------------
__global__ __launch_bounds__(256) void pool1_kernel(const float* __restrict__ y,
                                                    const int* __restrict__ gp,
                                                    float* __restrict__ partial) {
    const int g = blockIdx.x >> 4;
    const int s = blockIdx.x & 15;
    const int c = threadIdx.x & 127;
    const int q = threadIdx.x >> 7;  // 0..1
    const int rs = gp[g], re = gp[g + 1];
    float acc = 0.f;
    for (int r = rs + s * 2 + q; r < re; r += 32) acc += y[(size_t)r * kH + c];
    __shared__ float part[2][kH];
    part[q][c] = acc;
    __syncthreads();
    if (q == 0) partial[(size_t)blockIdx.x * kH + c] = part[0][c] + part[1][c];
}

__global__ void pool2_kernel(const float* __restrict__ partial, const int* __restrict__ gp,
                             float* __restrict__ out) {
    const int g = blockIdx.x;
    const int c = threadIdx.x;  // 128
    float v = 0.f;
#pragma unroll
    for (int s = 0; s < 16; ++s) v += partial[(size_t)((g << 4) + s) * kH + c];
    out[g * kH + c] = v / fmaxf((float)(gp[g + 1] - gp[g]), 1.0f);
}

// ---------------- BN (+ relu + residual for l>0), all-bf16 state + fp8 mirror ---------
__global__ __launch_bounds__(256) void bn_kernel(const uint2* __restrict__ h2b,
                                                 uint2* __restrict__ hb,
                                                 unsigned int* __restrict__ h8,
                                                 const float* __restrict__ gamma,
                                                 const float* __restrict__ beta,
                                                 const float* __restrict__ sums,
                                                 const float* __restrict__ sumsq,
                                                 int first, int last) {
    const float invN = 1.0f / (float)kN;
    const size_t total = (size_t)kN * (kH / 4);
    const size_t stride = (size_t)gridDim.x * blockDim.x;
    for (size_t i = (size_t)blockIdx.x * blockDim.x + threadIdx.x; i < total; i += stride) {
        int c0 = ((int)(i & 31)) * 4;
        float4 s4 = *reinterpret_cast<const float4*>(sums + c0);
        float4 q4 = *reinterpret_cast<const float4*>(sumsq + c0);
        float4 g4 = *reinterpret_cast<const float4*>(gamma + c0);
        float4 be4 = *reinterpret_cast<const float4*>(beta + c0);
        uint2 hv = h2b[i];
        float v0 = bf2f(hv.x & 0xffffu), v1 = bf2f(hv.x >> 16);
        float v2 = bf2f(hv.y & 0xffffu), v3 = bf2f(hv.y >> 16);
        float o0, o1, o2, o3;
        {
            float mu = s4.x * invN, var = fmaxf(q4.x * invN - mu * mu, 0.f);
            o0 = (v0 - mu) * rsqrtf(var + kBnEps) * g4.x + be4.x;
        }
        {
            float mu = s4.y * invN, var = fmaxf(q4.y * invN - mu * mu, 0.f);
            o1 = (v1 - mu) * rsqrtf(var + kBnEps) * g4.y + be4.y;
        }
        {
            float mu = s4.z * invN, var = fmaxf(q4.z * invN - mu * mu, 0.f);
            o2 = (v2 - mu) * rsqrtf(var + kBnEps) * g4.z + be4.z;
        }
        {
            float mu = s4.w * invN, var = fmaxf(q4.w * invN - mu * mu, 0.f);
            o3 = (v3 - mu) * rsqrtf(var + kBnEps) * g4.w + be4.w;
        }
        float r0, r1, r2, r3;
        if (first) {
            r0 = o0; r1 = o1; r2 = o2; r3 = o3;
        } else {
            uint2 pv = hb[i];
            r0 = bf2f(pv.x & 0xffffu) + fmaxf(o0, 0.f);
            r1 = bf2f(pv.x >> 16) + fmaxf(o1, 0.f);
            r2 = bf2f(pv.y & 0xffffu) + fmaxf(o2, 0.f);
            r3 = bf2f(pv.y >> 16) + fmaxf(o3, 0.f);
        }
        uint2 w;
        w.x = (unsigned int)f2bf(r0) | ((unsigned int)f2bf(r1) << 16);
        w.y = (unsigned int)f2bf(r2) | ((unsigned int)f2bf(r3) << 16);
        hb[i] = w;
        if (!last) {
            // fp8 mirror from the SAME rounded bf16 values the GEMM path sees
            h8[i] = pk_fp8(bf2f(w.x & 0xffffu), bf2f(w.x >> 16),
                           bf2f(w.y & 0xffffu), bf2f(w.y >> 16));
        }
    }
}

// ---------------- launch ----------------
extern "C" void kernel_launch(void* const* d_in, const int* in_sizes, int n_in,
                              void* d_out, int out_size, void* d_ws, size_t ws_size,
                              hipStream_t stream) {
    const float* x     = (const float*)d_in[0];
    const int*   ei    = (const int*)d_in[1];
    const int*   batch = (const int*)d_in[2];
    const float* W1    = (const float*)d_in[3];
    const float* b1    = (const float*)d_in[4];
    const float* W2    = (const float*)d_in[5];
    const float* b2    = (const float*)d_in[6];
    const float* gamma = (const float*)d_in[7];
    const float* beta  = (const float*)d_in[8];
    const float* eps   = (const float*)d_in[9];
    const float* linW  = (const float*)d_in[10];
    const float* linb  = (const float*)d_in[11];
    float* out = (float*)d_out;

    char* ws = (char*)d_ws;
    size_t off = 0;
    auto alloc = [&](size_t bytes) -> char* {
        char* p = ws + off;
        off = (off + bytes + 15) & ~(size_t)15;
        return p;
    };
    unsigned int*   hb     = (unsigned int*)alloc((size_t)kN * kH * 2);   // bf16 h state
    unsigned int*   h8     = (unsigned int*)alloc((size_t)kN * kH);       // fp8 gather mirror
    unsigned int*   aggb   = (unsigned int*)alloc((size_t)kN * kH * 2);   // bf16 agg
    unsigned short* hmid16 = (unsigned short*)alloc((size_t)kN * kH * 2); // bf16 MLP hidden
    unsigned short* h2b    = (unsigned short*)alloc((size_t)kN * kH * 2); // bf16 h2 (pre-BN)
    float* ybuf   = (float*)alloc((size_t)kN * kH * 4);  // final tanh output
    float* ppart  = (float*)alloc((size_t)kG * 16 * kH * 4);
    int*   rowptr = (int*)alloc((size_t)(kN + 1) * 4);
    int*   colidx = (int*)alloc((size_t)kE * 4);
    unsigned int* part = (unsigned int*)alloc((size_t)kE * 4);  // packed (dst<<16)|src
    int*   bh_in  = (int*)alloc((size_t)kM * 4);
    int*   bh_loc = (int*)alloc((size_t)kM * 4);
    int*   bh_ex  = (int*)alloc((size_t)kM * 4);
    int*   sbp    = (int*)alloc((size_t)128 * 4);
    float* stats  = (float*)alloc((size_t)kL * 256 * 4);
    float* spart  = (float*)alloc((size_t)kGemmGrid * 256 * 4);
    int*   gp     = (int*)alloc((size_t)(kG + 1) * 4);
    short* wpk    = (short*)alloc((size_t)11 * 16384 * 2);  // bf16 fragments

    const int* srcp = ei;       // edge_index[0] (source)
    const int* dstp = ei + kE;  // edge_index[1] (target)

    hipMemsetAsync(stats, 0, (size_t)kL * 256 * 4, stream);

    const int scanBlocks = (kM + 511) / 512;  // 75
    part1a_kernel<<<kG1, 256, 0, stream>>>(dstp, bh_in);
    scanP1_kernel<<<scanBlocks, 512, 0, stream>>>(bh_in, bh_loc, sbp, kM);
    scanP2_kernel<<<1, 128, 0, stream>>>(sbp, scanBlocks);
    scanP3_kernel<<<scanBlocks, 512, 0, stream>>>(bh_loc, sbp, bh_ex, kM);
    part1b_kernel<<<kG1, 256, 0, stream>>>(srcp, dstp, bh_ex, part);
    bucket_kernel<<<kB, 1024, 0, stream>>>(part, bh_ex, rowptr, colidx);
    gp_kernel<<<(kN + 255) / 256, 256, 0, stream>>>(batch, gp);
    pack_kernel<<<11, 256, 0, stream>>>(W1, W2, linW, wpk);
    conv_kernel<<<(kN * (kH / 4) + 255) / 256, 256, 0, stream>>>(x, hb, h8);

    for (int l = 0; l < kL; ++l) {
        gather_kernel<<<(kN + 3) / 4, 256, 0, stream>>>(h8, rowptr, colidx, (uint2*)aggb);
        mfma_gemm<0><<<kGemmGrid, 256, 0, stream>>>(
            (const unsigned short*)hb, (const unsigned short*)aggb, wpk, l,
            b1 + (size_t)l * kH, eps, l, nullptr, hmid16, nullptr);
        mfma_gemm<1><<<kGemmGrid, 256, 0, stream>>>(
            hmid16, nullptr, wpk, 5 + l, b2 + (size_t)l * kH, nullptr, 0, nullptr, h2b,
            spart);
        stats3_kernel<<<64, 256, 0, stream>>>(spart, stats + l * 256);
        bn_kernel<<<2048, 256, 0, stream>>>((const uint2*)h2b, (uint2*)hb, h8,
                                            gamma + (size_t)l * kH, beta + (size_t)l * kH,
                                            stats + l * 256, stats + l * 256 + 128,
                                            l == 0 ? 1 : 0, l == kL - 1 ? 1 : 0);
    }
    mfma_gemm<2><<<kGemmGrid, 256, 0, stream>>>((const unsigned short*)hb, nullptr, wpk, 10,
                                                linb, nullptr, 0, ybuf, nullptr, nullptr);
    pool1_kernel<<<kG * 16, 256, 0, stream>>>(ybuf, gp, ppart);
    pool2_kernel<<<kG, kH, 0, stream>>>(ppart, gp, out);
}

// Round 16
// 397.179 us; speedup vs baseline: 1.1942x; 1.0197x over previous
//
#include <hip/hip_runtime.h>
#include <cstddef>

// GIN forward on MI355X — round 16: accuracy-neutral trims on the R15 structure.
//  (a) final linear writes packed bf16 (reuses hmid16); pool1 reads bf16 (halves I/O)
//  (b) scanP2+P3 merged (each block wave-reduces the <=75 raw block totals itself)
// fp8 gather mirror kept (absmax 1.56e-2 < 1.875e-2, deterministic pipeline).

namespace {
constexpr int kN = 50000;
constexpr int kE = 800000;
constexpr int kH = 128;
constexpr int kL = 5;
constexpr int kG = 64;
constexpr float kBnEps = 1e-5f;
constexpr int kEPB = 1024;                      // edges per pass-1 block
constexpr int kG1 = (kE + kEPB - 1) / kEPB;     // 782
constexpr int kB = 49;                          // buckets: dst>>10, dst<50000
constexpr int kM = kB * kG1;                    // 38318 scan length
constexpr int kTiles = kN / 16;                 // 3125
constexpr int kGemmGrid = (kTiles + 3) / 4;     // 782
}

typedef __attribute__((ext_vector_type(8))) short short8v;
typedef __attribute__((ext_vector_type(4))) float f32x4;

__device__ inline unsigned short f2bf(float f) {
    unsigned int u = __float_as_uint(f);
    unsigned int r = (u + 0x7fffu + ((u >> 16) & 1u)) >> 16;  // round-to-nearest-even
    return (unsigned short)r;
}
__device__ inline float bf2f(unsigned int h16) {
    return __uint_as_float(h16 << 16);
}
// pack 4 floats -> 4 fp8 e4m3 (OCP on gfx950), RNE
__device__ inline unsigned int pk_fp8(float a, float b, float c, float d) {
    int p = 0;
    p = __builtin_amdgcn_cvt_pk_fp8_f32(a, b, p, false);
    p = __builtin_amdgcn_cvt_pk_fp8_f32(c, d, p, true);
    return (unsigned int)p;
}

// ---------------- CSR build, pass 1a: per-block bucket histogram ----------------
__global__ __launch_bounds__(256) void part1a_kernel(const int* __restrict__ dst,
                                                     int* __restrict__ bh) {
    __shared__ int hist[kB];
    const int tid = threadIdx.x;
    if (tid < kB) hist[tid] = 0;
    __syncthreads();
    const int base = blockIdx.x * kEPB;
    for (int i = tid; i < kEPB; i += 256) {
        int e = base + i;
        if (e < kE) atomicAdd(&hist[dst[e] >> 10], 1);
    }
    __syncthreads();
    if (tid < kB) bh[tid * kG1 + blockIdx.x] = hist[tid];  // bucket-major for flat scan
}

// ---------------- scan phase 1: per-block exclusive scan, raw block totals ----------
__global__ __launch_bounds__(512) void scanP1_kernel(const int* __restrict__ in,
                                                     int* __restrict__ loc,
                                                     int* __restrict__ bsum, int n) {
    const int i = blockIdx.x * 512 + threadIdx.x;
    const int lane = threadIdx.x & 63;
    const int wid = threadIdx.x >> 6;
    int v = (i < n) ? in[i] : 0;
    int s = v;
#pragma unroll
    for (int d = 1; d < 64; d <<= 1) {
        int t = __shfl_up(s, d);
        if (lane >= d) s += t;
    }
    __shared__ int wsum[8];
    if (lane == 63) wsum[wid] = s;
    __syncthreads();
    if (threadIdx.x < 8) {
        int w = wsum[threadIdx.x];
#pragma unroll
        for (int d = 1; d < 8; d <<= 1) {
            int t = __shfl_up(w, d);
            if (lane >= d) w += t;
        }
        wsum[threadIdx.x] = w;
    }
    __syncthreads();
    int woff = (wid == 0) ? 0 : wsum[wid - 1];
    int incl = s + woff;
    if (i < n) loc[i] = incl - v;
    if (threadIdx.x == 511) bsum[blockIdx.x] = incl;
}

// ---------------- scan phases 2+3 merged: each block derives its own prefix ---------
__global__ __launch_bounds__(512) void scanP23_kernel(const int* __restrict__ loc,
                                                      const int* __restrict__ bsum,
                                                      int* __restrict__ outp, int n) {
    __shared__ int spre;
    if (threadIdx.x < 64) {
        int lane = threadIdx.x;
        int a = 0;
        for (int j = lane; j < (int)blockIdx.x; j += 64) a += bsum[j];
#pragma unroll
        for (int d = 1; d < 64; d <<= 1) a += __shfl_xor(a, d);
        if (lane == 0) spre = a;
    }
    __syncthreads();
    const int i = blockIdx.x * 512 + threadIdx.x;
    if (i < n) outp[i] = loc[i] + spre;
}

// ---------------- CSR build, pass 1b: partition edges into buckets ----------------
__global__ __launch_bounds__(256) void part1b_kernel(const int* __restrict__ src,
                                                     const int* __restrict__ dst,
                                                     const int* __restrict__ bhex,
                                                     unsigned int* __restrict__ part) {
    __shared__ int cur[kB];
    const int tid = threadIdx.x;
    if (tid < kB) cur[tid] = bhex[tid * kG1 + blockIdx.x];
    __syncthreads();
    const int base = blockIdx.x * kEPB;
    for (int i = tid; i < kEPB; i += 256) {
        int e = base + i;
        if (e < kE) {
            unsigned int d = (unsigned int)dst[e];
            unsigned int s = (unsigned int)src[e];
            int p = atomicAdd(&cur[d >> 10], 1);
            part[p] = (d << 16) | s;
        }
    }
}

// ---------------- CSR build, pass 2: per-bucket local CSR (rowptr + col) ----------------
__global__ __launch_bounds__(1024) void bucket_kernel(const unsigned int* __restrict__ part,
                                                      const int* __restrict__ bhex,
                                                      int* __restrict__ rowptr,
                                                      int* __restrict__ col) {
    const int b = blockIdx.x;  // 0..48
    const int tid = threadIdx.x;
    const int lane = tid & 63;
    const int wid = tid >> 6;  // 0..15
    const int bstart = bhex[b * kG1];
    const int bend = (b == kB - 1) ? kE : bhex[(b + 1) * kG1];
    __shared__ int lhist[1024];
    __shared__ int wsum[16];
    lhist[tid] = 0;
    __syncthreads();
    for (int e = bstart + tid; e < bend; e += 1024)
        atomicAdd(&lhist[part[e] >> 16 & 1023], 1);
    __syncthreads();
    int v = lhist[tid];
    int s = v;
#pragma unroll
    for (int d = 1; d < 64; d <<= 1) {
        int t = __shfl_up(s, d);
        if (lane >= d) s += t;
    }
    if (lane == 63) wsum[wid] = s;
    __syncthreads();
    if (tid < 16) {
        int w = wsum[tid];
#pragma unroll
        for (int d = 1; d < 16; d <<= 1) {
            int t = __shfl_up(w, d);
            if (lane >= d) w += t;
        }
        wsum[tid] = w;
    }
    __syncthreads();
    int excl = s - v + ((wid == 0) ? 0 : wsum[wid - 1]);
    const int d = (b << 10) + tid;
    if (d < kN) rowptr[d] = bstart + excl;
    __syncthreads();
    lhist[tid] = bstart + excl;  // cursor
    __syncthreads();
    for (int e = bstart + tid; e < bend; e += 1024) {
        unsigned int pv = part[e];
        int p = atomicAdd(&lhist[pv >> 16 & 1023], 1);
        col[p] = (int)(pv & 0xffffu);
    }
    if (b == kB - 1 && tid == 0) rowptr[kN] = kE;
}

// batch is sorted: gp[g] = first row index of graph g, gp[kG] = kN. No atomics.
__global__ void gp_kernel(const int* __restrict__ batch, int* __restrict__ gp) {
    int i = blockIdx.x * blockDim.x + threadIdx.x;
    if (i >= kN) return;
    int b = batch[i];
    if (i == 0) {
        for (int g = 0; g <= b; ++g) gp[g] = 0;
    } else {
        int p = batch[i - 1];
        for (int g = p; g < b; ++g) gp[g + 1] = i;
    }
    if (i == kN - 1) {
        for (int g = b; g < kG; ++g) gp[g + 1] = kN;
    }
}

// ---------------- weight pre-pack: 11 matrices -> MFMA fragment order, bf16 ----
__global__ __launch_bounds__(256) void pack_kernel(const float* __restrict__ W1,
                                                   const float* __restrict__ W2,
                                                   const float* __restrict__ linW,
                                                   short* __restrict__ wpk) {
    const int m = blockIdx.x;  // 0..10
    const float* src = (m < 5) ? W1 + (size_t)m * 16384
                               : (m < 10 ? W2 + (size_t)(m - 5) * 16384 : linW);
    for (int f = threadIdx.x; f < 2048; f += 256) {
        int kc = f >> 9;
        int t = (f >> 6) & 7;
        int l = f & 63;
        int kr = kc * 32 + ((l >> 4) << 3);
        int cl = t * 16 + (l & 15);
        short8v hi;
#pragma unroll
        for (int e = 0; e < 8; ++e)
            hi[e] = (short)f2bf(src[(size_t)(kr + e) * kH + cl]);
        *reinterpret_cast<short8v*>(wpk + (size_t)m * 16384 + (size_t)f * 8) = hi;
    }
}

// ---------------- x -> bf16 h state + fp8 gather mirror (layer 0 only) ----------------
__global__ __launch_bounds__(256) void conv_kernel(const float* __restrict__ x,
                                                   unsigned int* __restrict__ hb,
                                                   unsigned int* __restrict__ h8) {
    int i = blockIdx.x * blockDim.x + threadIdx.x;  // over kN*32 float4s
    if (i >= kN * (kH / 4)) return;
    float4 v = reinterpret_cast<const float4*>(x)[i];
    unsigned int p01 = (unsigned int)f2bf(v.x) | ((unsigned int)f2bf(v.y) << 16);
    unsigned int p23 = (unsigned int)f2bf(v.z) | ((unsigned int)f2bf(v.w) << 16);
    hb[i * 2] = p01;
    hb[i * 2 + 1] = p23;
    h8[i] = pk_fp8(v.x, v.y, v.z, v.w);
}

// ---------------- aggregation: aggb[n] = bf16( sum_{j in N(n)} fp8 h8[col[j]] ) ------
__global__ __launch_bounds__(256) void gather_kernel(const unsigned int* __restrict__ h8,
                                                     const int* __restrict__ rowptr,
                                                     const int* __restrict__ col,
                                                     uint2* __restrict__ aggb2) {
    const int lane = threadIdx.x & 63;
    const int sub = lane >> 5;   // edge parity group
    const int cl = lane & 31;    // uint column group (4 fp8 = cols 4cl..4cl+3)
    const int n = blockIdx.x * 4 + (threadIdx.x >> 6);
    if (n >= kN) return;
    const int e0 = rowptr[n], e1 = rowptr[n + 1];
    if (e0 == e1) {
        if (sub == 0) aggb2[(size_t)n * 32 + cl] = make_uint2(0u, 0u);
        return;
    }
    const int last = e1 - 1;
    float a0 = 0.f, a1 = 0.f, a2 = 0.f, a3 = 0.f;
    float b0 = 0.f, b1 = 0.f, b2 = 0.f, b3 = 0.f;
    for (int e = e0; e < e1; e += 16) {
        int idx[8];
        float msk[8];
#pragma unroll
        for (int j = 0; j < 8; ++j) {
            int t = e + 2 * j + sub;
            msk[j] = (t <= last) ? 1.f : 0.f;
            idx[j] = col[t <= last ? t : last];
        }
        unsigned int v[8];
#pragma unroll
        for (int j = 0; j < 8; ++j) v[j] = h8[(size_t)idx[j] * 32 + cl];
#pragma unroll
        for (int j = 0; j < 8; ++j) {
            float x0 = __builtin_amdgcn_cvt_f32_fp8((int)v[j], 0);
            float x1 = __builtin_amdgcn_cvt_f32_fp8((int)v[j], 1);
            float x2 = __builtin_amdgcn_cvt_f32_fp8((int)v[j], 2);
            float x3 = __builtin_amdgcn_cvt_f32_fp8((int)v[j], 3);
            if (j & 1) {
                b0 = fmaf(msk[j], x0, b0); b1 = fmaf(msk[j], x1, b1);
                b2 = fmaf(msk[j], x2, b2); b3 = fmaf(msk[j], x3, b3);
            } else {
                a0 = fmaf(msk[j], x0, a0); a1 = fmaf(msk[j], x1, a1);
                a2 = fmaf(msk[j], x2, a2); a3 = fmaf(msk[j], x3, a3);
            }
        }
    }
    float s0 = a0 + b0, s1 = a1 + b1, s2 = a2 + b2, s3 = a3 + b3;
    s0 += __shfl_xor(s0, 32);
    s1 += __shfl_xor(s1, 32);
    s2 += __shfl_xor(s2, 32);
    s3 += __shfl_xor(s3, 32);
    if (sub == 0) {
        uint2 w;
        w.x = (unsigned int)f2bf(s0) | ((unsigned int)f2bf(s1) << 16);
        w.y = (unsigned int)f2bf(s2) | ((unsigned int)f2bf(s3) << 16);
        aggb2[(size_t)n * 32 + cl] = w;
    }
}

// ---------------- MFMA GEMM: one wave = 16 rows x 128 cols, all-bf16, 1-term ----------
// MODE 0: A = bf16( (1+eps)*Aa + Ab ) -> relu -> bf16 out16 (hmid)
// MODE 1: A = Aa direct -> relu -> bf16 out16 (h2) + per-block stats partials
// MODE 2: A = Aa direct -> tanh -> bf16 out16 (y)
template <int MODE>
__global__ __launch_bounds__(256) void mfma_gemm(const unsigned short* __restrict__ Aa,
                                                 const unsigned short* __restrict__ Ab,
                                                 const short* __restrict__ wpk, int mat,
                                                 const float* __restrict__ bias,
                                                 const float* __restrict__ eps_p, int layer,
                                                 unsigned short* __restrict__ out16,
                                                 float* __restrict__ spart) {
    const int lane = threadIdx.x & 63;
    const int wid = threadIdx.x >> 6;
    const int tile = blockIdx.x * 4 + wid;
    const bool valid = (tile < kTiles);
    if (MODE != 1 && !valid) return;
    const int row0 = tile * 16;
    const int m15 = lane & 15;
    const int kg = lane >> 4;  // 0..3
    const int arow = row0 + m15;

    float scale = 1.0f;
    if (MODE == 0) scale = 1.0f + eps_p[layer];

    const short8v* wp = reinterpret_cast<const short8v*>(wpk + (size_t)mat * 16384);

    f32x4 acc[8];
#pragma unroll
    for (int t = 0; t < 8; ++t) acc[t] = (f32x4)0.0f;

    if (valid) {
#pragma unroll
        for (int kc = 0; kc < 4; ++kc) {
            short8v ah;
            if (MODE == 0) {
                short8v hv = *reinterpret_cast<const short8v*>(Aa + (size_t)arow * kH +
                                                               kc * 32 + kg * 8);
                short8v gv = *reinterpret_cast<const short8v*>(Ab + (size_t)arow * kH +
                                                               kc * 32 + kg * 8);
#pragma unroll
                for (int e = 0; e < 8; ++e) {
                    float a = fmaf(scale, bf2f((unsigned short)hv[e]),
                                   bf2f((unsigned short)gv[e]));
                    ah[e] = (short)f2bf(a);
                }
            } else {
                ah = *reinterpret_cast<const short8v*>(Aa + (size_t)arow * kH + kc * 32 +
                                                       kg * 8);
            }
#pragma unroll
            for (int t = 0; t < 8; ++t) {
                int f = (kc * 8 + t) * 64 + lane;
                acc[t] = __builtin_amdgcn_mfma_f32_16x16x32_bf16(ah, wp[f], acc[t], 0, 0, 0);
            }
        }
    }

    const int orow0 = row0 + kg * 4;
    if (MODE == 0) {
#pragma unroll
        for (int t = 0; t < 8; ++t) {
            int cl = t * 16 + m15;
            float b = bias[cl];
#pragma unroll
            for (int r = 0; r < 4; ++r)
                out16[(size_t)(orow0 + r) * kH + cl] = f2bf(fmaxf(acc[t][r] + b, 0.f));
        }
    } else if (MODE == 2) {
#pragma unroll
        for (int t = 0; t < 8; ++t) {
            int cl = t * 16 + m15;
            float b = bias[cl];
#pragma unroll
            for (int r = 0; r < 4; ++r)
                out16[(size_t)(orow0 + r) * kH + cl] = f2bf(tanhf(acc[t][r] + b));
        }
    } else {
        __shared__ float sst[4][kH], sqt[4][kH];
#pragma unroll
        for (int t = 0; t < 8; ++t) {
            int cl = t * 16 + m15;
            float b = bias[cl];
            float st = 0.f, qt = 0.f;
#pragma unroll
            for (int r = 0; r < 4; ++r) {
                float o = fmaxf(acc[t][r] + b, 0.f);
                unsigned short h16 = f2bf(o);
                if (valid) out16[(size_t)(orow0 + r) * kH + cl] = h16;
                float orr = bf2f(h16);  // stats from the rounded value bn will read
                st += orr;
                qt = fmaf(orr, orr, qt);
            }
            if (!valid) { st = 0.f; qt = 0.f; }
            st += __shfl_xor(st, 16); st += __shfl_xor(st, 32);
            qt += __shfl_xor(qt, 16); qt += __shfl_xor(qt, 32);
            if (kg == 0) { sst[wid][cl] = st; sqt[wid][cl] = qt; }
        }
        __syncthreads();
        int c = threadIdx.x;
        float v;
        if (c < kH) v = sst[0][c] + sst[1][c] + sst[2][c] + sst[3][c];
        else { int cc = c - kH; v = sqt[0][cc] + sqt[1][cc] + sqt[2][cc] + sqt[3][cc]; }
        spart[(size_t)blockIdx.x * 256 + c] = v;
    }
}

// ---------------- fold per-block partials into stats (sums[128] | sumsq[128]) ----------
__global__ __launch_bounds__(256) void stats3_kernel(const float* __restrict__ spart,
                                                     float* __restrict__ stats) {
    const int c = threadIdx.x;  // 0..255
    float s = 0.f;
    for (int k = blockIdx.x; k < kGemmGrid; k += gridDim.x)
        s += spart[(size_t)k * 256 + c];
    atomicAdd(&stats[c], s);
}

// ---------------- two-phase segment mean pool (bf16 input) ----------------
__global__ __launch_bounds__(256) void pool1_kernel(const unsigned int* __restrict__ y16,
                                                    const int* __restrict__ gp,
                                                    float* __restrict__ partial) {
    const int g = blockIdx.x >> 4;
    const int s = blockIdx.x & 15;
    const int k = threadIdx.x & 63;  // u32 index (2 cols)
    const int q = threadIdx.x >> 6;  // 0..3 row subgroup
    const int rs = gp[g], re = gp[g + 1];
    float s0 = 0.f, s1 = 0.f;
    for (int r = rs + s * 4 + q; r < re; r += 64) {
        unsigned int u = y16[(size_t)r * 64 + k];
        s0 += bf2f(u & 0xffffu);
        s1 += bf2f(u >> 16);
    }
    __shared__ float part[4][64][2];
    part[q][k][0] = s0;
    part[q][k][1] = s1;
    __syncthreads();
    if (q == 0) {
        float v0 = part[0][k][0] + part[1][k][0] + part[2][k][0] + part[3][k][0];
        float v1 = part[0][k][1] + part[1][k][1] + part[2][k][1] + part[3][k][1];
        partial[(size_t)blockIdx.x * kH + 2 * k] = v0;
        partial[(size_t)blockIdx.x * kH + 2 * k + 1] = v1;
    }
}

__global__ void pool2_kernel(const float* __restrict__ partial, const int* __restrict__ gp,
                             float* __restrict__ out) {
    const int g = blockIdx.x;
    const int c = threadIdx.x;  // 128
    float v = 0.f;
#pragma unroll
    for (int s = 0; s < 16; ++s) v += partial[(size_t)((g << 4) + s) * kH + c];
    out[g * kH + c] = v / fmaxf((float)(gp[g + 1] - gp[g]), 1.0f);
}

// ---------------- BN (+ relu + residual for l>0), all-bf16 state + fp8 mirror ---------
__global__ __launch_bounds__(256) void bn_kernel(const uint2* __restrict__ h2b,
                                                 uint2* __restrict__ hb,
                                                 unsigned int* __restrict__ h8,
                                                 const float* __restrict__ gamma,
                                                 const float* __restrict__ beta,
                                                 const float* __restrict__ sums,
                                                 const float* __restrict__ sumsq,
                                                 int first, int last) {
    const float invN = 1.0f / (float)kN;
    const size_t total = (size_t)kN * (kH / 4);
    const size_t stride = (size_t)gridDim.x * blockDim.x;
    for (size_t i = (size_t)blockIdx.x * blockDim.x + threadIdx.x; i < total; i += stride) {
        int c0 = ((int)(i & 31)) * 4;
        float4 s4 = *reinterpret_cast<const float4*>(sums + c0);
        float4 q4 = *reinterpret_cast<const float4*>(sumsq + c0);
        float4 g4 = *reinterpret_cast<const float4*>(gamma + c0);
        float4 be4 = *reinterpret_cast<const float4*>(beta + c0);
        uint2 hv = h2b[i];
        float v0 = bf2f(hv.x & 0xffffu), v1 = bf2f(hv.x >> 16);
        float v2 = bf2f(hv.y & 0xffffu), v3 = bf2f(hv.y >> 16);
        float o0, o1, o2, o3;
        {
            float mu = s4.x * invN, var = fmaxf(q4.x * invN - mu * mu, 0.f);
            o0 = (v0 - mu) * rsqrtf(var + kBnEps) * g4.x + be4.x;
        }
        {
            float mu = s4.y * invN, var = fmaxf(q4.y * invN - mu * mu, 0.f);
            o1 = (v1 - mu) * rsqrtf(var + kBnEps) * g4.y + be4.y;
        }
        {
            float mu = s4.z * invN, var = fmaxf(q4.z * invN - mu * mu, 0.f);
            o2 = (v2 - mu) * rsqrtf(var + kBnEps) * g4.z + be4.z;
        }
        {
            float mu = s4.w * invN, var = fmaxf(q4.w * invN - mu * mu, 0.f);
            o3 = (v3 - mu) * rsqrtf(var + kBnEps) * g4.w + be4.w;
        }
        float r0, r1, r2, r3;
        if (first) {
            r0 = o0; r1 = o1; r2 = o2; r3 = o3;
        } else {
            uint2 pv = hb[i];
            r0 = bf2f(pv.x & 0xffffu) + fmaxf(o0, 0.f);
            r1 = bf2f(pv.x >> 16) + fmaxf(o1, 0.f);
            r2 = bf2f(pv.y & 0xffffu) + fmaxf(o2, 0.f);
            r3 = bf2f(pv.y >> 16) + fmaxf(o3, 0.f);
        }
        uint2 w;
        w.x = (unsigned int)f2bf(r0) | ((unsigned int)f2bf(r1) << 16);
        w.y = (unsigned int)f2bf(r2) | ((unsigned int)f2bf(r3) << 16);
        hb[i] = w;
        if (!last) {
            h8[i] = pk_fp8(bf2f(w.x & 0xffffu), bf2f(w.x >> 16),
                           bf2f(w.y & 0xffffu), bf2f(w.y >> 16));
        }
    }
}

// ---------------- launch ----------------
extern "C" void kernel_launch(void* const* d_in, const int* in_sizes, int n_in,
                              void* d_out, int out_size, void* d_ws, size_t ws_size,
                              hipStream_t stream) {
    const float* x     = (const float*)d_in[0];
    const int*   ei    = (const int*)d_in[1];
    const int*   batch = (const int*)d_in[2];
    const float* W1    = (const float*)d_in[3];
    const float* b1    = (const float*)d_in[4];
    const float* W2    = (const float*)d_in[5];
    const float* b2    = (const float*)d_in[6];
    const float* gamma = (const float*)d_in[7];
    const float* beta  = (const float*)d_in[8];
    const float* eps   = (const float*)d_in[9];
    const float* linW  = (const float*)d_in[10];
    const float* linb  = (const float*)d_in[11];
    float* out = (float*)d_out;

    char* ws = (char*)d_ws;
    size_t off = 0;
    auto alloc = [&](size_t bytes) -> char* {
        char* p = ws + off;
        off = (off + bytes + 15) & ~(size_t)15;
        return p;
    };
    unsigned int*   hb     = (unsigned int*)alloc((size_t)kN * kH * 2);   // bf16 h state
    unsigned int*   h8     = (unsigned int*)alloc((size_t)kN * kH);       // fp8 gather mirror
    unsigned int*   aggb   = (unsigned int*)alloc((size_t)kN * kH * 2);   // bf16 agg
    unsigned short* hmid16 = (unsigned short*)alloc((size_t)kN * kH * 2); // bf16 hidden / y
    unsigned short* h2b    = (unsigned short*)alloc((size_t)kN * kH * 2); // bf16 h2 (pre-BN)
    float* ppart  = (float*)alloc((size_t)kG * 16 * kH * 4);
    int*   rowptr = (int*)alloc((size_t)(kN + 1) * 4);
    int*   colidx = (int*)alloc((size_t)kE * 4);
    unsigned int* part = (unsigned int*)alloc((size_t)kE * 4);  // packed (dst<<16)|src
    int*   bh_in  = (int*)alloc((size_t)kM * 4);
    int*   bh_loc = (int*)alloc((size_t)kM * 4);
    int*   bh_ex  = (int*)alloc((size_t)kM * 4);
    int*   sbp    = (int*)alloc((size_t)128 * 4);
    float* stats  = (float*)alloc((size_t)kL * 256 * 4);
    float* spart  = (float*)alloc((size_t)kGemmGrid * 256 * 4);
    int*   gp     = (int*)alloc((size_t)(kG + 1) * 4);
    short* wpk    = (short*)alloc((size_t)11 * 16384 * 2);  // bf16 fragments

    const int* srcp = ei;       // edge_index[0] (source)
    const int* dstp = ei + kE;  // edge_index[1] (target)

    hipMemsetAsync(stats, 0, (size_t)kL * 256 * 4, stream);

    const int scanBlocks = (kM + 511) / 512;  // 75
    part1a_kernel<<<kG1, 256, 0, stream>>>(dstp, bh_in);
    scanP1_kernel<<<scanBlocks, 512, 0, stream>>>(bh_in, bh_loc, sbp, kM);
    scanP23_kernel<<<scanBlocks, 512, 0, stream>>>(bh_loc, sbp, bh_ex, kM);
    part1b_kernel<<<kG1, 256, 0, stream>>>(srcp, dstp, bh_ex, part);
    bucket_kernel<<<kB, 1024, 0, stream>>>(part, bh_ex, rowptr, colidx);
    gp_kernel<<<(kN + 255) / 256, 256, 0, stream>>>(batch, gp);
    pack_kernel<<<11, 256, 0, stream>>>(W1, W2, linW, wpk);
    conv_kernel<<<(kN * (kH / 4) + 255) / 256, 256, 0, stream>>>(x, hb, h8);

    for (int l = 0; l < kL; ++l) {
        gather_kernel<<<(kN + 3) / 4, 256, 0, stream>>>(h8, rowptr, colidx, (uint2*)aggb);
        mfma_gemm<0><<<kGemmGrid, 256, 0, stream>>>(
            (const unsigned short*)hb, (const unsigned short*)aggb, wpk, l,
            b1 + (size_t)l * kH, eps, l, hmid16, nullptr);
        mfma_gemm<1><<<kGemmGrid, 256, 0, stream>>>(
            hmid16, nullptr, wpk, 5 + l, b2 + (size_t)l * kH, nullptr, 0, h2b, spart);
        stats3_kernel<<<64, 256, 0, stream>>>(spart, stats + l * 256);
        bn_kernel<<<2048, 256, 0, stream>>>((const uint2*)h2b, (uint2*)hb, h8,
                                            gamma + (size_t)l * kH, beta + (size_t)l * kH,
                                            stats + l * 256, stats + l * 256 + 128,
                                            l == 0 ? 1 : 0, l == kL - 1 ? 1 : 0);
    }
    mfma_gemm<2><<<kGemmGrid, 256, 0, stream>>>((const unsigned short*)hb, nullptr, wpk, 10,
                                                linb, nullptr, 0, hmid16, nullptr);
    pool1_kernel<<<kG * 16, 256, 0, stream>>>((const unsigned int*)hmid16, gp, ppart);
    pool2_kernel<<<kG, kH, 0, stream>>>(ppart, gp, out);
}